// Round 16
// baseline (48.398 us; speedup 1.0000x reference)
//
#include <hip/hip_runtime.h>

// SSIM loss, fused. in: f32 (16,3,512,512) x2; out: f32[16].
//
// r16 = r15's full-width wave (8 cols/lane, 64 lanes = 512 cols) repacked
// for residency. Evidence: 1-wave blocks cap at ~8 waves/CU (r12/r13/r15
// occupancy data -> per-CU workgroup-slot limit); multi-wave blocks reach
// 14+ (r3). So: WPB=4 (4 strips of one image per block), RPS=4 ->
// 1536 blocks = 6/CU x 4 waves = up to 24 waves/CU (3x r15).
//  * Per wave: vertical sliding 11-row column sums {s1,s2,sp,sq} for its
//    8 cols (32 regs); NEW rows 2-deep (n0,n1), OLD 1-deep (o0) -> 48 buf
//    regs (r15 had 80; target VGPR <=85 for 6 waves/SIMD).
//  * Per STEP: publish 8 col-quads to wave-private LDS slice (Q[i*64+t],
//    conflict-free), 10 b128 halo reads, in-register window slide,
//    scale-folded SSIM. No __syncthreads (wave-private LDS + lgkmcnt).
//  * NEW prefetched 2 STEPs ahead; OLD issued at STEP top (L2, ~300cyc).
//  * XCD-pinned img%8, band-major. Banked double atomics + finalize.

namespace {
constexpr int BATCH = 16;
constexpr int CHAN  = 3;
constexpr int HDIM  = 512;
constexpr int WDIM  = 512;
constexpr int WIN   = 11;
constexpr int HO    = HDIM - WIN + 1;   // 502
constexpr int WO    = WDIM - WIN + 1;   // 502
constexpr int RPS   = 4;
constexpr int NSBLK = 32;               // strip-blocks per image (128 slots)
constexpr int WPB   = 4;
constexpr int NTHR  = WPB * 64;         // 256
constexpr int NIMG  = BATCH * CHAN;     // 48
constexpr int NBLK  = NIMG * NSBLK;     // 1536
constexpr int NBANK = 16;
// scale-folded constants: C*121^2 (121^4 cancels in n/d)
constexpr float K1 = 6.5025f  * 14641.0f;
constexpr float K2 = 58.5225f * 14641.0f;
constexpr float W2F = 121.0f;
}

__global__ __launch_bounds__(NTHR) void ssim_main(
    const float* __restrict__ g1, const float* __restrict__ g2,
    double* __restrict__ ws) {
  __shared__ float4 Qs[WPB * 512];       // 32 KB: 8KB slice per wave

  const int t  = threadIdx.x & 63;       // lane
  const int wv = threadIdx.x >> 6;       // wave in block
  // XCD-pinned, band-major: img%8 == blockIdx%8
  const int xcd  = blockIdx.x & 7;
  const int q    = blockIdx.x >> 3;      // 0..191
  const int g    = q % (NIMG / 8);       // 0..5  (image within XCD, fast)
  const int sblk = q / (NIMG / 8);       // 0..31 (band, slow)
  const int img  = g * 8 + xcd;          // 0..47
  const int b    = img / CHAN;

  const int strip = sblk * WPB + wv;     // 0..127
  const int r0 = strip * RPS;
  if (r0 >= HO) return;                  // slots 126,127 idle
  const int r1 = min(r0 + RPS, HO);

  const int c0 = 8 * t;                  // lane's first col
  const int tp1 = (t + 1) & 63;          // halo lanes (wrap -> masked cols)
  const int tp2 = (t + 2) & 63;
  float4* __restrict__ Q = Qs + wv * 512;

  const float* __restrict__ p1 = g1 + (size_t)img * HDIM * WDIM + c0;
  const float* __restrict__ p2 = g2 + (size_t)img * HDIM * WDIM + c0;

  float s1[8], s2[8], sp[8], sq[8];
#pragma unroll
  for (int k = 0; k < 8; ++k) s1[k] = s2[k] = sp[k] = sq[k] = 0.f;

#define DECL_SLOT(p) float4 p##u0, p##u1, p##v0, p##v1;
  DECL_SLOT(n0) DECL_SLOT(n1) DECL_SLOT(o0)

#define LD(p, row)                                          \
  {                                                         \
    const float* q1_ = p1 + (size_t)(row) * WDIM;           \
    const float* q2_ = p2 + (size_t)(row) * WDIM;           \
    p##u0 = *(const float4*)q1_;                            \
    p##u1 = *(const float4*)(q1_ + 4);                      \
    p##v0 = *(const float4*)q2_;                            \
    p##v1 = *(const float4*)(q2_ + 4);                      \
  }

#define ACC8(p)                                                          \
  {                                                                      \
    float uu[8] = {p##u0.x, p##u0.y, p##u0.z, p##u0.w,                   \
                   p##u1.x, p##u1.y, p##u1.z, p##u1.w};                  \
    float vv[8] = {p##v0.x, p##v0.y, p##v0.z, p##v0.w,                   \
                   p##v1.x, p##v1.y, p##v1.z, p##v1.w};                  \
    _Pragma("unroll") for (int k_ = 0; k_ < 8; ++k_) {                   \
      float x = uu[k_], y = vv[k_];                                      \
      s1[k_] += x;                                                       \
      s2[k_] += y;                                                       \
      sp[k_] = fmaf(x, y, sp[k_]);                                       \
      sq[k_] = fmaf(x, x, sq[k_]);                                       \
      sq[k_] = fmaf(y, y, sq[k_]);                                       \
    }                                                                    \
  }

#define SUB8(p)                                                          \
  {                                                                      \
    float uu[8] = {p##u0.x, p##u0.y, p##u0.z, p##u0.w,                   \
                   p##u1.x, p##u1.y, p##u1.z, p##u1.w};                  \
    float vv[8] = {p##v0.x, p##v0.y, p##v0.z, p##v0.w,                   \
                   p##v1.x, p##v1.y, p##v1.z, p##v1.w};                  \
    _Pragma("unroll") for (int k_ = 0; k_ < 8; ++k_) {                   \
      float x = uu[k_], y = vv[k_];                                      \
      s1[k_] -= x;                                                       \
      s2[k_] -= y;                                                       \
      sp[k_] = fmaf(x, -y, sp[k_]);                                      \
      sq[k_] = fmaf(x, -x, sq[k_]);                                      \
      sq[k_] = fmaf(y, -y, sq[k_]);                                      \
    }                                                                    \
  }

  // ---- warm-up: accumulate rows r0..r0+9, 2-deep pipeline ----
  // (max row touched: r0+11 = 511 at the last strip; in-bounds)
  LD(n0, r0) LD(n1, r0 + 1)
  ACC8(n0) LD(n0, r0 + 2)
  ACC8(n1) LD(n1, r0 + 3)
  ACC8(n0) LD(n0, r0 + 4)
  ACC8(n1) LD(n1, r0 + 5)
  ACC8(n0) LD(n0, r0 + 6)
  ACC8(n1) LD(n1, r0 + 7)
  ACC8(n0) LD(n0, r0 + 8)
  ACC8(n1) LD(n1, r0 + 9)
  ACC8(n0) LD(n0, r0 + 10)
  ACC8(n1) LD(n1, r0 + 11)
  // accumulated r0..r0+9; n0 = r0+10, n1 = r0+11

  float acc = 0.f;

#define DOSTEP(pn, r_)                                                   \
  {                                                                      \
    const int rr = (r_);                                                 \
    ACC8(pn)                            /* window = rows [rr, rr+10] */  \
    LD(pn, min(rr + 12, HDIM - 1))      /* NEW for STEP rr+2 */          \
    LD(o0, rr)                          /* OLD (L2 hit), used at end */  \
    _Pragma("unroll") for (int i_ = 0; i_ < 8; ++i_)                     \
        Q[i_ * 64 + t] = make_float4(s1[i_], s2[i_], sp[i_], sq[i_]);    \
    asm volatile("s_waitcnt lgkmcnt(0)" ::: "memory");                   \
    float4 h[10];                                                        \
    _Pragma("unroll") for (int m_ = 0; m_ < 8; ++m_)                     \
        h[m_] = Q[m_ * 64 + tp1];                                        \
    h[8] = Q[tp2];                                                       \
    h[9] = Q[64 + tp2];                                                  \
    float w1 = ((s1[0] + s1[1]) + (s1[2] + s1[3])) +                     \
               ((s1[4] + s1[5]) + (s1[6] + s1[7])) +                     \
               ((h[0].x + h[1].x) + h[2].x);                             \
    float w2 = ((s2[0] + s2[1]) + (s2[2] + s2[3])) +                     \
               ((s2[4] + s2[5]) + (s2[6] + s2[7])) +                     \
               ((h[0].y + h[1].y) + h[2].y);                             \
    float wp = ((sp[0] + sp[1]) + (sp[2] + sp[3])) +                     \
               ((sp[4] + sp[5]) + (sp[6] + sp[7])) +                     \
               ((h[0].z + h[1].z) + h[2].z);                             \
    float wq = ((sq[0] + sq[1]) + (sq[2] + sq[3])) +                     \
               ((sq[4] + sq[5]) + (sq[6] + sq[7])) +                     \
               ((h[0].w + h[1].w) + h[2].w);                             \
    _Pragma("unroll") for (int j_ = 0; j_ < 8; ++j_) {                   \
      if (j_ > 0) {                                                      \
        w1 = (w1 - s1[j_ - 1]) + h[j_ + 2].x;                            \
        w2 = (w2 - s2[j_ - 1]) + h[j_ + 2].y;                            \
        wp = (wp - sp[j_ - 1]) + h[j_ + 2].z;                            \
        wq = (wq - sq[j_ - 1]) + h[j_ + 2].w;                            \
      }                                                                  \
      float s12 = w1 * w2;                                               \
      float msq = fmaf(w1, w1, w2 * w2);                                 \
      float N1_ = fmaf(2.f, s12, K1);                                    \
      float N2_ = fmaf(2.f, fmaf(W2F, wp, -s12), K2);                    \
      float D1_ = msq + K1;                                              \
      float D2_ = fmaf(W2F, wq, -msq) + K2;                              \
      float val = (N1_ * N2_) * __builtin_amdgcn_rcpf(D1_ * D2_);        \
      acc += (c0 + j_ < WO) ? val : 0.f;                                 \
    }                                                                    \
    SUB8(o0)                            /* remove row rr */              \
  }

  // ---- main loop: 4 STEPs, NEW slot alternating n0/n1 ----
  DOSTEP(n0, r0)
  if (r0 + 1 < r1) DOSTEP(n1, r0 + 1)
  if (r0 + 2 < r1) DOSTEP(n0, r0 + 2)
  if (r0 + 3 < r1) DOSTEP(n1, r0 + 3)
#undef DOSTEP
#undef SUB8
#undef ACC8
#undef LD
#undef DECL_SLOT

  // wave reduction, banked double atomic
#pragma unroll
  for (int off = 32; off > 0; off >>= 1) acc += __shfl_down(acc, off, 64);
  if (t == 0)
    atomicAdd(&ws[b * NBANK + ((blockIdx.x * WPB + wv) & (NBANK - 1))],
              (double)acc);
}

__global__ void ssim_finalize(const double* __restrict__ ws,
                              float* __restrict__ out) {
  int i = threadIdx.x;
  if (i < BATCH) {
    double s = 0.0;
#pragma unroll
    for (int k = 0; k < NBANK; ++k) s += ws[i * NBANK + k];
    out[i] = (float)(1.0 - s / ((double)CHAN * HO * WO));
  }
}

extern "C" void kernel_launch(void* const* d_in, const int* in_sizes, int n_in,
                              void* d_out, int out_size, void* d_ws,
                              size_t ws_size, hipStream_t stream) {
  const float* img1 = (const float*)d_in[0];
  const float* img2 = (const float*)d_in[1];
  float* out = (float*)d_out;
  double* ws = (double*)d_ws;

  hipMemsetAsync(d_ws, 0, BATCH * NBANK * sizeof(double), stream);
  ssim_main<<<dim3(NBLK), NTHR, 0, stream>>>(img1, img2, ws);
  ssim_finalize<<<1, 64, 0, stream>>>(ws, out);
}